// Round 1
// baseline (2474.763 us; speedup 1.0000x reference)
//
#include <hip/hip_runtime.h>

// Problem constants (from reference): B=2, S=2048, H=1024, NUM_HEAD=16, HEAD=64
#define BATCH 2
#define S_LEN 2048
#define HDIM  1024
#define NHEAD 16
#define HD    64
#define NEGBIAS -1e10f

// ---------------------------------------------------------------------------
// Kernel A: projection GEMM.  Y = X @ W^T + bias, written in [B, NH, S, HD]
// layout for the attention kernel.  M = B*S = 4096, N = K = 1024.
// 64x64 tile per block, 256 threads, 4x4 micro-tile per thread, K-tile = 16.
// ---------------------------------------------------------------------------
__global__ __launch_bounds__(256) void proj_gemm(const float* __restrict__ X,
                                                 const float* __restrict__ W,
                                                 const float* __restrict__ bias,
                                                 float* __restrict__ Y)
{
    const int Kd = HDIM;
    const int tile_n = blockIdx.x;   // 16 tiles over N=1024
    const int tile_m = blockIdx.y;   // 64 tiles over M=4096

    __shared__ float Xs[16][66];     // [k][m], pad to dodge bank conflicts
    __shared__ float Ws[16][66];     // [k][n]

    const int t  = threadIdx.x;
    const int tx = t & 15;           // n-direction
    const int ty = t >> 4;           // m-direction

    float acc[4][4];
#pragma unroll
    for (int i = 0; i < 4; i++)
#pragma unroll
        for (int j = 0; j < 4; j++) acc[i][j] = 0.f;

    const int m0 = tile_m * 64;
    const int n0 = tile_n * 64;

    for (int k0 = 0; k0 < Kd; k0 += 16) {
        // stage 64x16 tiles of X and W (both row-major along k -> coalesced)
#pragma unroll
        for (int i = 0; i < 4; i++) {
            int e = t + 256 * i;          // 0..1023
            int m = e >> 4;               // 0..63
            int k = e & 15;               // 0..15
            Xs[k][m] = X[(size_t)(m0 + m) * Kd + (k0 + k)];
            Ws[k][m] = W[(size_t)(n0 + m) * Kd + (k0 + k)];
        }
        __syncthreads();

#pragma unroll
        for (int kk = 0; kk < 16; kk++) {
            float a[4], bv[4];
#pragma unroll
            for (int i = 0; i < 4; i++) a[i]  = Xs[kk][ty * 4 + i];
#pragma unroll
            for (int j = 0; j < 4; j++) bv[j] = Ws[kk][tx * 4 + j];
#pragma unroll
            for (int i = 0; i < 4; i++)
#pragma unroll
                for (int j = 0; j < 4; j++) acc[i][j] += a[i] * bv[j];
        }
        __syncthreads();
    }

    // epilogue: add bias, scatter into [B, NH, S, HD] layout
#pragma unroll
    for (int i = 0; i < 4; i++) {
        int m = m0 + ty * 4 + i;          // global row = b*S + s
        int b = m >> 11;                  // /2048
        int s = m & (S_LEN - 1);
#pragma unroll
        for (int j = 0; j < 4; j++) {
            int n = n0 + tx * 4 + j;      // = h*HD + d
            int h = n >> 6;
            int d = n & (HD - 1);
            float v = acc[i][j] + bias[n];
            Y[(((size_t)b * NHEAD + h) * S_LEN + s) * HD + d] = v;
        }
    }
}

// ---------------------------------------------------------------------------
// Kernel B: flash-style attention.  One block per (b, h, 32 query rows).
// 256 threads: 8 threads per query row, each owns 8 score columns / 8 output
// dims.  K/V tiles of 64 rows staged in LDS; online softmax (m,l per row,
// replicated across the row's 8 lanes via shfl_xor reductions).
// ---------------------------------------------------------------------------
#define QT 32
#define KT 64

__global__ __launch_bounds__(256) void flash_attn(const float* __restrict__ Q,
                                                  const float* __restrict__ K,
                                                  const float* __restrict__ V,
                                                  const int* __restrict__ mask,
                                                  float* __restrict__ out)
{
    const int bid = blockIdx.x;
    const int qt  = bid & (S_LEN / QT - 1);     // 0..63
    const int bh  = bid >> 6;                   // 0..31
    const int h   = bh & (NHEAD - 1);
    const int b   = bh >> 4;

    const float* Qbase = Q + ((size_t)bh * S_LEN + qt * QT) * HD;
    const float* Kbase = K + (size_t)bh * S_LEN * HD;
    const float* Vbase = V + (size_t)bh * S_LEN * HD;

    __shared__ float Qs[QT][HD + 1];
    __shared__ float Ks[KT][HD + 1];
    __shared__ float Vs[KT][HD + 1];
    __shared__ float Ps[QT][KT + 1];

    const int t  = threadIdx.x;
    const int r  = t >> 3;       // query row 0..31
    const int c8 = t & 7;        // column-slice 0..7

    // stage Q tile (coalesced, contiguous)
    for (int i = t; i < QT * HD; i += 256)
        Qs[i >> 6][i & (HD - 1)] = Qbase[i];

    float m_run = -3.0e38f;
    float l_run = 0.f;
    float o_acc[8];
#pragma unroll
    for (int j = 0; j < 8; j++) o_acc[j] = 0.f;

    __syncthreads();

    for (int kt = 0; kt < S_LEN; kt += KT) {
        // stage K/V tiles
        for (int i = t; i < KT * HD; i += 256) {
            int rr = i >> 6, cc = i & (HD - 1);
            size_t g = (size_t)(kt + rr) * HD + cc;
            Ks[rr][cc] = Kbase[g];
            Vs[rr][cc] = Vbase[g];
        }
        __syncthreads();

        // scores for row r, columns c8*8 .. c8*8+7
        float s[8];
#pragma unroll
        for (int j = 0; j < 8; j++) s[j] = 0.f;
        for (int d = 0; d < HD; d++) {
            float qv = Qs[r][d];
#pragma unroll
            for (int j = 0; j < 8; j++) s[j] += qv * Ks[c8 * 8 + j][d];
        }
#pragma unroll
        for (int j = 0; j < 8; j++) {
            int mk = mask[b * S_LEN + kt + c8 * 8 + j];
            s[j] += mk ? 0.f : NEGBIAS;
        }

        // row max across 8 owned cols then across the row's 8 lanes
        float mt = s[0];
#pragma unroll
        for (int j = 1; j < 8; j++) mt = fmaxf(mt, s[j]);
        mt = fmaxf(mt, __shfl_xor(mt, 1));
        mt = fmaxf(mt, __shfl_xor(mt, 2));
        mt = fmaxf(mt, __shfl_xor(mt, 4));

        float m_new  = fmaxf(m_run, mt);
        float alpha  = __expf(m_run - m_new);
        float lsum = 0.f;
#pragma unroll
        for (int j = 0; j < 8; j++) {
            s[j] = __expf(s[j] - m_new);
            lsum += s[j];
        }
        lsum += __shfl_xor(lsum, 1);
        lsum += __shfl_xor(lsum, 2);
        lsum += __shfl_xor(lsum, 4);
        l_run = l_run * alpha + lsum;
        m_run = m_new;

        // publish P, rescale O
#pragma unroll
        for (int j = 0; j < 8; j++) Ps[r][c8 * 8 + j] = s[j];
#pragma unroll
        for (int j = 0; j < 8; j++) o_acc[j] *= alpha;
        __syncthreads();

        // O[r][c8*8+j] += sum_c P[r][c] * V[c][c8*8+j]
        for (int c = 0; c < KT; c++) {
            float p = Ps[r][c];
#pragma unroll
            for (int j = 0; j < 8; j++) o_acc[j] += p * Vs[c][c8 * 8 + j];
        }
        __syncthreads();   // protect Ks/Vs/Ps before next iteration
    }

    // write out [B, S, H] fp32
    float inv_l = 1.f / l_run;
    size_t obase = ((size_t)b * S_LEN + qt * QT + r) * HDIM + h * HD + c8 * 8;
#pragma unroll
    for (int j = 0; j < 8; j++) out[obase + j] = o_acc[j] * inv_l;
}

// ---------------------------------------------------------------------------
extern "C" void kernel_launch(void* const* d_in, const int* in_sizes, int n_in,
                              void* d_out, int out_size, void* d_ws, size_t ws_size,
                              hipStream_t stream) {
    const float* query = (const float*)d_in[0];
    const float* key   = (const float*)d_in[1];
    const float* value = (const float*)d_in[2];
    const int*   mask  = (const int*)  d_in[3];
    const float* Wq    = (const float*)d_in[4];
    const float* bq    = (const float*)d_in[5];
    const float* Wk    = (const float*)d_in[6];
    const float* bk    = (const float*)d_in[7];
    const float* Wv    = (const float*)d_in[8];
    const float* bv    = (const float*)d_in[9];
    float* out = (float*)d_out;

    const size_t nElem = (size_t)BATCH * S_LEN * HDIM;   // 4M floats each
    if (ws_size < 3 * nElem * sizeof(float)) return;     // need 48 MB scratch
    float* Qb = (float*)d_ws;
    float* Kb = Qb + nElem;
    float* Vb = Kb + nElem;

    dim3 gproj(HDIM / 64, (BATCH * S_LEN) / 64);         // (16, 64)
    proj_gemm<<<gproj, 256, 0, stream>>>(query, Wq, bq, Qb);
    proj_gemm<<<gproj, 256, 0, stream>>>(key,   Wk, bk, Kb);
    proj_gemm<<<gproj, 256, 0, stream>>>(value, Wv, bv, Vb);

    flash_attn<<<BATCH * NHEAD * (S_LEN / QT), 256, 0, stream>>>(Qb, Kb, Vb, mask, out);
}

// Round 4
// 289.133 us; speedup vs baseline: 8.5592x; 8.5592x over previous
//
#include <hip/hip_runtime.h>

// B=2, S=2048, H=1024, NUM_HEAD=16, HEAD=64
#define BATCH 2
#define S_LEN 2048
#define HDIM  1024
#define NHEAD 16
#define HD    64
#define NEGBIAS -1e10f

typedef __attribute__((ext_vector_type(8))) _Float16 half8;  // 8 f16 in 4 VGPRs
typedef __attribute__((ext_vector_type(4))) float   f32x4;   // MFMA C/D frag

// ---------------------------------------------------------------------------
// Fused projection GEMM (fp16 MFMA): Y = X @ W^T + b.
// M=4096 (b*S+s), N=1024 (h*64+d), K=1024.  grid.z selects q/k/v.
// z=0,1 -> write [B,NH,S,HD]; z=2 -> write V transposed [B,NH,HD,S].
// 128x128 tile, BK=32, 256 thr = 4 waves, each wave 64x64 (4x4 MFMA frags).
// fp32 inputs are converted to fp16 inline while staging to LDS.
// ---------------------------------------------------------------------------
__global__ __launch_bounds__(256) void proj_gemm_f16(
    const float* __restrict__ Xq, const float* __restrict__ Wq, const float* __restrict__ bq,
    const float* __restrict__ Xk, const float* __restrict__ Wk, const float* __restrict__ bk,
    const float* __restrict__ Xv, const float* __restrict__ Wv, const float* __restrict__ bv,
    _Float16* __restrict__ Qb, _Float16* __restrict__ Kb, _Float16* __restrict__ Vtb)
{
    const int z = blockIdx.z;
    const float* X    = (z == 0) ? Xq : (z == 1) ? Xk : Xv;
    const float* W    = (z == 0) ? Wq : (z == 1) ? Wk : Wv;
    const float* bias = (z == 0) ? bq : (z == 1) ? bk : bv;
    _Float16* Y       = (z == 0) ? Qb : (z == 1) ? Kb : Vtb;

    const int n0 = blockIdx.x * 128;
    const int m0 = blockIdx.y * 128;

    __shared__ __align__(16) _Float16 As[128][40];  // [m][k], pad 40
    __shared__ __align__(16) _Float16 Bs[128][40];  // [n][k]

    const int t    = threadIdx.x;
    const int w    = t >> 6;
    const int lane = t & 63;
    const int quad = lane >> 4;
    const int lc   = lane & 15;
    const int wm   = (w >> 1) * 64;
    const int wn   = (w & 1) * 64;

    const f32x4 fzero = {0.f, 0.f, 0.f, 0.f};
    f32x4 acc[4][4];
#pragma unroll
    for (int i = 0; i < 4; i++)
#pragma unroll
        for (int j = 0; j < 4; j++) acc[i][j] = fzero;

    const int srow = t >> 2;   // 0..63 (two halves: srow, srow+64)
    const int sc   = t & 3;    // 8-elem chunk within the 32-elem k slice

    for (int k0 = 0; k0 < HDIM; k0 += 32) {
        // stage A and B tiles (128 rows x 32 k each), fp32 -> fp16
#pragma unroll
        for (int half = 0; half < 2; half++) {
            int row = srow + half * 64;
            {
                const float* g = X + (size_t)(m0 + row) * HDIM + k0 + sc * 8;
                float4 a0 = *(const float4*)g;
                float4 a1 = *(const float4*)(g + 4);
                half8 v;
                v[0] = (_Float16)a0.x; v[1] = (_Float16)a0.y;
                v[2] = (_Float16)a0.z; v[3] = (_Float16)a0.w;
                v[4] = (_Float16)a1.x; v[5] = (_Float16)a1.y;
                v[6] = (_Float16)a1.z; v[7] = (_Float16)a1.w;
                *(half8*)&As[row][sc * 8] = v;
            }
            {
                const float* g = W + (size_t)(n0 + row) * HDIM + k0 + sc * 8;
                float4 a0 = *(const float4*)g;
                float4 a1 = *(const float4*)(g + 4);
                half8 v;
                v[0] = (_Float16)a0.x; v[1] = (_Float16)a0.y;
                v[2] = (_Float16)a0.z; v[3] = (_Float16)a0.w;
                v[4] = (_Float16)a1.x; v[5] = (_Float16)a1.y;
                v[6] = (_Float16)a1.z; v[7] = (_Float16)a1.w;
                *(half8*)&Bs[row][sc * 8] = v;
            }
        }
        __syncthreads();

        half8 af[4], bf[4];
#pragma unroll
        for (int mt = 0; mt < 4; mt++)
            af[mt] = *(const half8*)&As[wm + mt * 16 + lc][quad * 8];
#pragma unroll
        for (int nt = 0; nt < 4; nt++)
            bf[nt] = *(const half8*)&Bs[wn + nt * 16 + lc][quad * 8];
#pragma unroll
        for (int mt = 0; mt < 4; mt++)
#pragma unroll
            for (int nt = 0; nt < 4; nt++)
                acc[mt][nt] = __builtin_amdgcn_mfma_f32_16x16x32_f16(
                    af[mt], bf[nt], acc[mt][nt], 0, 0, 0);
        __syncthreads();
    }

    // epilogue: bias, fp16, route per mode
#pragma unroll
    for (int nt = 0; nt < 4; nt++) {
        const int n = n0 + wn + nt * 16 + lc;          // h*64 + d
        const float bv_ = bias[n];
        const int h = n >> 6, d = n & 63;
#pragma unroll
        for (int mt = 0; mt < 4; mt++) {
#pragma unroll
            for (int r = 0; r < 4; r++) {
                const int m = m0 + wm + mt * 16 + quad * 4 + r;   // b*S + s
                const int b = m >> 11, s = m & (S_LEN - 1);
                const int bh = b * NHEAD + h;
                _Float16 val = (_Float16)(acc[mt][nt][r] + bv_);
                if (z == 2)
                    Y[((size_t)bh * HD + d) * S_LEN + s] = val;          // V^T
                else
                    Y[((size_t)bh * S_LEN + s) * HD + d] = val;          // Q,K
            }
        }
    }
}

// ---------------------------------------------------------------------------
// Flash attention, fp16 MFMA 16x16x32.  One block = (b,h, 64 q-rows), 4 waves
// x 16 rows.  K/V tiles of 64 staged in LDS (padded rows).  Q frags in regs.
// Scores in C-layout (row=quad*4+reg, col=lane&15); softmax reductions via
// shfl_xor 1/2/4/8; P round-trips through per-wave LDS into A-layout for PV.
// ---------------------------------------------------------------------------
__global__ __launch_bounds__(256) void flash_attn_mfma(
    const _Float16* __restrict__ Qb, const _Float16* __restrict__ Kb,
    const _Float16* __restrict__ Vtb, const int* __restrict__ mask,
    float* __restrict__ out)
{
    const int qt = blockIdx.x & 31;      // 32 q-tiles of 64
    const int bh = blockIdx.x >> 5;      // 0..31
    const int b  = bh >> 4;
    const int h  = bh & (NHEAD - 1);

    __shared__ __align__(16) _Float16 Ks [64][72];      // [key][d]
    __shared__ __align__(16) _Float16 Vts[64][72];      // [d][key]
    __shared__ __align__(16) _Float16 Ps [4][16][72];   // per-wave P

    const int t    = threadIdx.x;
    const int w    = t >> 6;
    const int lane = t & 63;
    const int quad = lane >> 4;
    const int lc   = lane & 15;

    const _Float16* Kbase = Kb  + (size_t)bh * S_LEN * HD;
    const _Float16* Vbase = Vtb + (size_t)bh * HD * S_LEN;

    // Q fragments (A-layout): m=lc, k = s*32 + quad*8 + j
    const int qrow = qt * 64 + w * 16 + lc;
    half8 qf[2];
#pragma unroll
    for (int s = 0; s < 2; s++)
        qf[s] = *(const half8*)(Qb + ((size_t)bh * S_LEN + qrow) * HD + s * 32 + quad * 8);

    const f32x4 fzero = {0.f, 0.f, 0.f, 0.f};
    f32x4 o[4];
#pragma unroll
    for (int nt = 0; nt < 4; nt++) o[nt] = fzero;
    float mrun[4] = {-3.0e38f, -3.0e38f, -3.0e38f, -3.0e38f};
    float lrun[4] = {0.f, 0.f, 0.f, 0.f};

    for (int kt = 0; kt < S_LEN; kt += 64) {
        // stage full 64x64 K tile and 64x64 Vt tile:
        // 512 chunks of 8 f16 each per tile; 256 threads x 2 chunks
#pragma unroll
        for (int i = 0; i < 2; i++) {
            int c  = t + 256 * i;        // 0..511
            int rr = c >> 3;             // 0..63
            int cc = (c & 7) * 8;        // 0..56
            *(half8*)&Ks[rr][cc] =
                *(const half8*)(Kbase + (size_t)(kt + rr) * HD + cc);
            *(half8*)&Vts[rr][cc] =
                *(const half8*)(Vbase + (size_t)rr * S_LEN + kt + cc);
        }
        __syncthreads();

        // QK^T: 4 key-tiles x 2 k-steps
        f32x4 scf[4];
#pragma unroll
        for (int tt = 0; tt < 4; tt++) scf[tt] = fzero;
#pragma unroll
        for (int s = 0; s < 2; s++) {
#pragma unroll
            for (int tt = 0; tt < 4; tt++) {
                half8 kf = *(const half8*)&Ks[tt * 16 + lc][s * 32 + quad * 8];
                scf[tt] = __builtin_amdgcn_mfma_f32_16x16x32_f16(qf[s], kf, scf[tt], 0, 0, 0);
            }
        }

        // mask bias (col = key = kt + tt*16 + lc, shared by all 4 regs)
        float mb[4];
#pragma unroll
        for (int tt = 0; tt < 4; tt++)
            mb[tt] = mask[b * S_LEN + kt + tt * 16 + lc] ? 0.f : NEGBIAS;
#pragma unroll
        for (int tt = 0; tt < 4; tt++)
#pragma unroll
            for (int r = 0; r < 4; r++) scf[tt][r] += mb[tt];

        // online softmax per q-row (reg r); row lives in 16 lanes of one quad
#pragma unroll
        for (int r = 0; r < 4; r++) {
            float mx = scf[0][r];
#pragma unroll
            for (int tt = 1; tt < 4; tt++) mx = fmaxf(mx, scf[tt][r]);
            mx = fmaxf(mx, __shfl_xor(mx, 1));
            mx = fmaxf(mx, __shfl_xor(mx, 2));
            mx = fmaxf(mx, __shfl_xor(mx, 4));
            mx = fmaxf(mx, __shfl_xor(mx, 8));
            float mn = fmaxf(mrun[r], mx);
            float al = __expf(mrun[r] - mn);
            float ls = 0.f;
#pragma unroll
            for (int tt = 0; tt < 4; tt++) {
                float p = __expf(scf[tt][r] - mn);
                scf[tt][r] = p;
                ls += p;
            }
            ls += __shfl_xor(ls, 1);
            ls += __shfl_xor(ls, 2);
            ls += __shfl_xor(ls, 4);
            ls += __shfl_xor(ls, 8);
            lrun[r] = lrun[r] * al + ls;
            mrun[r] = mn;
#pragma unroll
            for (int nt = 0; nt < 4; nt++) o[nt][r] *= al;
        }

        // P (C-layout) -> per-wave LDS -> A-layout
#pragma unroll
        for (int tt = 0; tt < 4; tt++)
#pragma unroll
            for (int r = 0; r < 4; r++)
                Ps[w][quad * 4 + r][tt * 16 + lc] = (_Float16)scf[tt][r];

        // PV: O[16x64] += P[16x64] * V[64x64]
#pragma unroll
        for (int s = 0; s < 2; s++) {
            half8 pf = *(const half8*)&Ps[w][lc][s * 32 + quad * 8];
#pragma unroll
            for (int nt = 0; nt < 4; nt++) {
                half8 vf = *(const half8*)&Vts[nt * 16 + lc][s * 32 + quad * 8];
                o[nt] = __builtin_amdgcn_mfma_f32_16x16x32_f16(pf, vf, o[nt], 0, 0, 0);
            }
        }
        __syncthreads();
    }

    // epilogue: out[b][s][h*64+d] fp32
#pragma unroll
    for (int r = 0; r < 4; r++) {
        const int s_ = qt * 64 + w * 16 + quad * 4 + r;
        const float inv = 1.f / lrun[r];
        const size_t rowb = ((size_t)b * S_LEN + s_) * HDIM + h * HD;
#pragma unroll
        for (int nt = 0; nt < 4; nt++)
            out[rowb + nt * 16 + lc] = o[nt][r] * inv;
    }
}

// ---------------------------------------------------------------------------
extern "C" void kernel_launch(void* const* d_in, const int* in_sizes, int n_in,
                              void* d_out, int out_size, void* d_ws, size_t ws_size,
                              hipStream_t stream) {
    const float* query = (const float*)d_in[0];
    const float* key   = (const float*)d_in[1];
    const float* value = (const float*)d_in[2];
    const int*   mask  = (const int*)  d_in[3];
    const float* Wq    = (const float*)d_in[4];
    const float* bq    = (const float*)d_in[5];
    const float* Wk    = (const float*)d_in[6];
    const float* bk    = (const float*)d_in[7];
    const float* Wv    = (const float*)d_in[8];
    const float* bv    = (const float*)d_in[9];
    float* out = (float*)d_out;

    const size_t nElem = (size_t)BATCH * S_LEN * HDIM;          // 4M
    if (ws_size < 3 * nElem * sizeof(_Float16)) return;         // 24 MB
    _Float16* Qb  = (_Float16*)d_ws;
    _Float16* Kb  = Qb + nElem;
    _Float16* Vtb = Kb + nElem;

    dim3 gproj(HDIM / 128, (BATCH * S_LEN) / 128, 3);           // (8, 32, 3)
    proj_gemm_f16<<<gproj, 256, 0, stream>>>(query, Wq, bq, key, Wk, bk,
                                             value, Wv, bv, Qb, Kb, Vtb);

    flash_attn_mfma<<<BATCH * NHEAD * (S_LEN / 64), 256, 0, stream>>>(
        Qb, Kb, Vtb, mask, out);
}

// Round 5
// 252.106 us; speedup vs baseline: 9.8164x; 1.1469x over previous
//
#include <hip/hip_runtime.h>

// B=2, S=2048, H=1024, NUM_HEAD=16, HEAD=64
#define BATCH 2
#define S_LEN 2048
#define HDIM  1024
#define NHEAD 16
#define HD    64
#define NEGBIAS -1e10f

typedef __attribute__((ext_vector_type(8))) _Float16 half8;  // 8 f16 in 4 VGPRs
typedef __attribute__((ext_vector_type(4))) float   f32x4;   // MFMA C/D frag

// ---------------------------------------------------------------------------
// W pre-convert: fp32 -> fp16, once.  grid.y selects Wq/Wk/Wv.
// ---------------------------------------------------------------------------
__global__ __launch_bounds__(256) void cvt_w(
    const float* __restrict__ Wq, const float* __restrict__ Wk,
    const float* __restrict__ Wv, _Float16* __restrict__ Wf)
{
    const int z = blockIdx.y;
    const float* src = (z == 0) ? Wq : (z == 1) ? Wk : Wv;
    _Float16* dst = Wf + (size_t)z * (HDIM * HDIM);
    size_t i = ((size_t)blockIdx.x * 256 + threadIdx.x) * 8;   // 1M elems / 8
    float4 a0 = *(const float4*)(src + i);
    float4 a1 = *(const float4*)(src + i + 4);
    half8 v;
    v[0] = (_Float16)a0.x; v[1] = (_Float16)a0.y;
    v[2] = (_Float16)a0.z; v[3] = (_Float16)a0.w;
    v[4] = (_Float16)a1.x; v[5] = (_Float16)a1.y;
    v[6] = (_Float16)a1.z; v[7] = (_Float16)a1.w;
    *(half8*)(dst + i) = v;
}

// ---------------------------------------------------------------------------
// Fused projection GEMM (fp16 MFMA): Y = X @ W^T + b.  W pre-converted f16.
// z=0,1 -> write [B,NH,S,HD]; z=2 -> write V transposed [B,NH,HD,S].
// ---------------------------------------------------------------------------
__global__ __launch_bounds__(256) void proj_gemm_f16(
    const float* __restrict__ Xq, const float* __restrict__ Xk,
    const float* __restrict__ Xv, const _Float16* __restrict__ Wf,
    const float* __restrict__ bq, const float* __restrict__ bk,
    const float* __restrict__ bv,
    _Float16* __restrict__ Qb, _Float16* __restrict__ Kb, _Float16* __restrict__ Vtb)
{
    const int z = blockIdx.z;
    const float* X    = (z == 0) ? Xq : (z == 1) ? Xk : Xv;
    const float* bias = (z == 0) ? bq : (z == 1) ? bk : bv;
    const _Float16* Wz = Wf + (size_t)z * (HDIM * HDIM);
    _Float16* Y       = (z == 0) ? Qb : (z == 1) ? Kb : Vtb;

    const int n0 = blockIdx.x * 128;
    const int m0 = blockIdx.y * 128;

    __shared__ __align__(16) _Float16 As[128][40];  // [m][k], pad 40
    __shared__ __align__(16) _Float16 Bs[128][40];  // [n][k]

    const int t    = threadIdx.x;
    const int w    = t >> 6;
    const int lane = t & 63;
    const int quad = lane >> 4;
    const int lc   = lane & 15;
    const int wm   = (w >> 1) * 64;
    const int wn   = (w & 1) * 64;

    const f32x4 fzero = {0.f, 0.f, 0.f, 0.f};
    f32x4 acc[4][4];
#pragma unroll
    for (int i = 0; i < 4; i++)
#pragma unroll
        for (int j = 0; j < 4; j++) acc[i][j] = fzero;

    const int srow = t >> 2;   // 0..63 (two halves: srow, srow+64)
    const int sc   = t & 3;    // 8-elem chunk within the 32-elem k slice

    for (int k0 = 0; k0 < HDIM; k0 += 32) {
#pragma unroll
        for (int half = 0; half < 2; half++) {
            int row = srow + half * 64;
            {   // X: fp32 -> f16 inline
                const float* g = X + (size_t)(m0 + row) * HDIM + k0 + sc * 8;
                float4 a0 = *(const float4*)g;
                float4 a1 = *(const float4*)(g + 4);
                half8 v;
                v[0] = (_Float16)a0.x; v[1] = (_Float16)a0.y;
                v[2] = (_Float16)a0.z; v[3] = (_Float16)a0.w;
                v[4] = (_Float16)a1.x; v[5] = (_Float16)a1.y;
                v[6] = (_Float16)a1.z; v[7] = (_Float16)a1.w;
                *(half8*)&As[row][sc * 8] = v;
            }
            // W: already f16, straight 16B copy
            *(half8*)&Bs[row][sc * 8] =
                *(const half8*)(Wz + (size_t)(n0 + row) * HDIM + k0 + sc * 8);
        }
        __syncthreads();

        half8 af[4], bf[4];
#pragma unroll
        for (int mt = 0; mt < 4; mt++)
            af[mt] = *(const half8*)&As[wm + mt * 16 + lc][quad * 8];
#pragma unroll
        for (int nt = 0; nt < 4; nt++)
            bf[nt] = *(const half8*)&Bs[wn + nt * 16 + lc][quad * 8];
#pragma unroll
        for (int mt = 0; mt < 4; mt++)
#pragma unroll
            for (int nt = 0; nt < 4; nt++)
                acc[mt][nt] = __builtin_amdgcn_mfma_f32_16x16x32_f16(
                    af[mt], bf[nt], acc[mt][nt], 0, 0, 0);
        __syncthreads();
    }

#pragma unroll
    for (int nt = 0; nt < 4; nt++) {
        const int n = n0 + wn + nt * 16 + lc;          // h*64 + d
        const float bv_ = bias[n];
        const int h = n >> 6, d = n & 63;
#pragma unroll
        for (int mt = 0; mt < 4; mt++) {
#pragma unroll
            for (int r = 0; r < 4; r++) {
                const int m = m0 + wm + mt * 16 + quad * 4 + r;   // b*S + s
                const int b = m >> 11, s = m & (S_LEN - 1);
                const int bh = b * NHEAD + h;
                _Float16 val = (_Float16)(acc[mt][nt][r] + bv_);
                if (z == 2)
                    Y[((size_t)bh * HD + d) * S_LEN + s] = val;          // V^T
                else
                    Y[((size_t)bh * S_LEN + s) * HD + d] = val;          // Q,K
            }
        }
    }
}

// ---------------------------------------------------------------------------
// Flash attention, TRANSPOSED orientation: S^T = K.Q^T, O^T = V^T.P^T.
// C-layout column (lane&15) = query row -> each lane owns ONE q-row:
// softmax = in-register reduce over 16 + 2 shuffles (xor 16/32); m,l scalars.
// One block = (b,h,64 q-rows), 4 waves x 16 q.  K/V tiles of 64 in LDS.
// ---------------------------------------------------------------------------
__global__ __launch_bounds__(256) void flash_attn_mfma(
    const _Float16* __restrict__ Qb, const _Float16* __restrict__ Kb,
    const _Float16* __restrict__ Vtb, const int* __restrict__ mask,
    float* __restrict__ out)
{
    const int qt = blockIdx.x & 31;      // 32 q-tiles of 64
    const int bh = blockIdx.x >> 5;      // 0..31
    const int b  = bh >> 4;
    const int h  = bh & (NHEAD - 1);

    __shared__ __align__(16) _Float16 Ks [64][72];      // [key][d]
    __shared__ __align__(16) _Float16 Vts[64][72];      // [d][key]
    __shared__ __align__(16) _Float16 Ps [4][16][72];   // per-wave P, [q][key]
    __shared__ float biasS[64];                         // mask bias per key

    const int t    = threadIdx.x;
    const int w    = t >> 6;
    const int lane = t & 63;
    const int quad = lane >> 4;
    const int lc   = lane & 15;

    const _Float16* Kbase = Kb  + (size_t)bh * S_LEN * HD;
    const _Float16* Vbase = Vtb + (size_t)bh * HD * S_LEN;

    // Q fragment = MFMA B-operand: n = lc (q-row), k = s*32 + quad*8 + j
    const int qrow = qt * 64 + w * 16 + lc;
    half8 qf[2];
#pragma unroll
    for (int s = 0; s < 2; s++)
        qf[s] = *(const half8*)(Qb + ((size_t)bh * S_LEN + qrow) * HD + s * 32 + quad * 8);

    const f32x4 fzero = {0.f, 0.f, 0.f, 0.f};
    f32x4 o[4];                         // O^T: d = nt*16+quad*4+r, q = lc
#pragma unroll
    for (int nt = 0; nt < 4; nt++) o[nt] = fzero;
    float mrun = -3.0e38f;
    float lrun = 0.f;

    for (int kt = 0; kt < S_LEN; kt += 64) {
        // stage 64x64 K and Vt tiles (512 chunks of 16B each, 2 per thread)
#pragma unroll
        for (int i = 0; i < 2; i++) {
            int c  = t + 256 * i;        // 0..511
            int rr = c >> 3;             // 0..63
            int cc = (c & 7) * 8;        // 0..56
            *(half8*)&Ks[rr][cc] =
                *(const half8*)(Kbase + (size_t)(kt + rr) * HD + cc);
            *(half8*)&Vts[rr][cc] =
                *(const half8*)(Vbase + (size_t)rr * S_LEN + kt + cc);
        }
        if (t < 64) biasS[t] = mask[b * S_LEN + kt + t] ? 0.f : NEGBIAS;
        __syncthreads();

        // S^T = K.Q^T : A = K-frag (m=key), B = Q-frag (n=q)
        f32x4 scf[4];
#pragma unroll
        for (int tt = 0; tt < 4; tt++) scf[tt] = fzero;
#pragma unroll
        for (int s = 0; s < 2; s++) {
#pragma unroll
            for (int tt = 0; tt < 4; tt++) {
                half8 kf = *(const half8*)&Ks[tt * 16 + lc][s * 32 + quad * 8];
                scf[tt] = __builtin_amdgcn_mfma_f32_16x16x32_f16(kf, qf[s], scf[tt], 0, 0, 0);
            }
        }

        // mask bias: score (tt,r) is key tt*16+quad*4+r
#pragma unroll
        for (int tt = 0; tt < 4; tt++) {
            float4 b4 = *(const float4*)&biasS[tt * 16 + quad * 4];
            scf[tt][0] += b4.x; scf[tt][1] += b4.y;
            scf[tt][2] += b4.z; scf[tt][3] += b4.w;
        }

        // per-lane online softmax (q = lc); keys spread over 4 quad-lanes
        float mx = scf[0][0];
#pragma unroll
        for (int tt = 0; tt < 4; tt++)
#pragma unroll
            for (int r = 0; r < 4; r++) mx = fmaxf(mx, scf[tt][r]);
        mx = fmaxf(mx, __shfl_xor(mx, 16));
        mx = fmaxf(mx, __shfl_xor(mx, 32));

        float mn = fmaxf(mrun, mx);
        float al = __expf(mrun - mn);
        float ls = 0.f;
#pragma unroll
        for (int tt = 0; tt < 4; tt++)
#pragma unroll
            for (int r = 0; r < 4; r++) {
                float p = __expf(scf[tt][r] - mn);
                scf[tt][r] = p;
                ls += p;
            }
        ls += __shfl_xor(ls, 16);
        ls += __shfl_xor(ls, 32);
        lrun = lrun * al + ls;
        mrun = mn;
#pragma unroll
        for (int nt = 0; nt < 4; nt++) {
            o[nt][0] *= al; o[nt][1] *= al; o[nt][2] *= al; o[nt][3] *= al;
        }

        // P (q-major rows): Ps[w][q=lc][key]
#pragma unroll
        for (int tt = 0; tt < 4; tt++)
#pragma unroll
            for (int r = 0; r < 4; r++)
                Ps[w][lc][tt * 16 + quad * 4 + r] = (_Float16)scf[tt][r];

        // O^T += V^T.P^T : A = Vt-frag (m=d), B = P-frag (n=q)
#pragma unroll
        for (int s = 0; s < 2; s++) {
            half8 pf = *(const half8*)&Ps[w][lc][s * 32 + quad * 8];
#pragma unroll
            for (int nt = 0; nt < 4; nt++) {
                half8 vf = *(const half8*)&Vts[nt * 16 + lc][s * 32 + quad * 8];
                o[nt] = __builtin_amdgcn_mfma_f32_16x16x32_f16(vf, pf, o[nt], 0, 0, 0);
            }
        }
        __syncthreads();
    }

    // epilogue: lane owns q-row qrow; contiguous float4 stores
    const float inv = 1.f / lrun;
    const size_t rowb = ((size_t)b * S_LEN + qrow) * HDIM + h * HD;
#pragma unroll
    for (int nt = 0; nt < 4; nt++) {
        float4 v;
        v.x = o[nt][0] * inv; v.y = o[nt][1] * inv;
        v.z = o[nt][2] * inv; v.w = o[nt][3] * inv;
        *(float4*)&out[rowb + nt * 16 + quad * 4] = v;
    }
}

// ---------------------------------------------------------------------------
extern "C" void kernel_launch(void* const* d_in, const int* in_sizes, int n_in,
                              void* d_out, int out_size, void* d_ws, size_t ws_size,
                              hipStream_t stream) {
    const float* query = (const float*)d_in[0];
    const float* key   = (const float*)d_in[1];
    const float* value = (const float*)d_in[2];
    const int*   mask  = (const int*)  d_in[3];
    const float* Wq    = (const float*)d_in[4];
    const float* bq    = (const float*)d_in[5];
    const float* Wk    = (const float*)d_in[6];
    const float* bk    = (const float*)d_in[7];
    const float* Wv    = (const float*)d_in[8];
    const float* bv    = (const float*)d_in[9];
    float* out = (float*)d_out;

    const size_t nElem = (size_t)BATCH * S_LEN * HDIM;          // 4M
    const size_t wElem = (size_t)HDIM * HDIM;                   // 1M
    if (ws_size < (3 * nElem + 3 * wElem) * sizeof(_Float16)) return;  // 30 MB
    _Float16* Qb  = (_Float16*)d_ws;
    _Float16* Kb  = Qb + nElem;
    _Float16* Vtb = Kb + nElem;
    _Float16* Wf  = Vtb + nElem;

    dim3 gcvt(wElem / (256 * 8), 3);                            // (512, 3)
    cvt_w<<<gcvt, 256, 0, stream>>>(Wq, Wk, Wv, Wf);

    dim3 gproj(HDIM / 128, (BATCH * S_LEN) / 128, 3);           // (8, 32, 3)
    proj_gemm_f16<<<gproj, 256, 0, stream>>>(query, key, value, Wf,
                                             bq, bk, bv, Qb, Kb, Vtb);

    flash_attn_mfma<<<BATCH * NHEAD * (S_LEN / 64), 256, 0, stream>>>(
        Qb, Kb, Vtb, mask, out);
}

// Round 6
// 246.624 us; speedup vs baseline: 10.0346x; 1.0222x over previous
//
#include <hip/hip_runtime.h>

// B=2, S=2048, H=1024, NUM_HEAD=16, HEAD=64
#define BATCH 2
#define S_LEN 2048
#define HDIM  1024
#define NHEAD 16
#define HD    64
#define NEGBIAS -1e10f

typedef __attribute__((ext_vector_type(8))) _Float16 half8;  // 8 f16 in 4 VGPRs
typedef __attribute__((ext_vector_type(4))) _Float16 half4;  // 4 f16 in 2 VGPRs
typedef __attribute__((ext_vector_type(4))) float   f32x4;   // MFMA C/D frag

// ---------------------------------------------------------------------------
// W pre-convert: fp32 -> fp16, once.  grid.y selects Wq/Wk/Wv.
// ---------------------------------------------------------------------------
__global__ __launch_bounds__(256) void cvt_w(
    const float* __restrict__ Wq, const float* __restrict__ Wk,
    const float* __restrict__ Wv, _Float16* __restrict__ Wf)
{
    const int z = blockIdx.y;
    const float* src = (z == 0) ? Wq : (z == 1) ? Wk : Wv;
    _Float16* dst = Wf + (size_t)z * (HDIM * HDIM);
    size_t i = ((size_t)blockIdx.x * 256 + threadIdx.x) * 8;   // 1M elems / 8
    float4 a0 = *(const float4*)(src + i);
    float4 a1 = *(const float4*)(src + i + 4);
    half8 v;
    v[0] = (_Float16)a0.x; v[1] = (_Float16)a0.y;
    v[2] = (_Float16)a0.z; v[3] = (_Float16)a0.w;
    v[4] = (_Float16)a1.x; v[5] = (_Float16)a1.y;
    v[6] = (_Float16)a1.z; v[7] = (_Float16)a1.w;
    *(half8*)(dst + i) = v;
}

// ---------------------------------------------------------------------------
// Fused projection GEMM (fp16 MFMA): Y = X @ W^T + b.  W pre-converted f16.
// z=0,1 -> write [B,NH,S,HD]; z=2 -> write V transposed [B,NH,HD,S].
// ---------------------------------------------------------------------------
__global__ __launch_bounds__(256) void proj_gemm_f16(
    const float* __restrict__ Xq, const float* __restrict__ Xk,
    const float* __restrict__ Xv, const _Float16* __restrict__ Wf,
    const float* __restrict__ bq, const float* __restrict__ bk,
    const float* __restrict__ bv,
    _Float16* __restrict__ Qb, _Float16* __restrict__ Kb, _Float16* __restrict__ Vtb)
{
    const int z = blockIdx.z;
    const float* X    = (z == 0) ? Xq : (z == 1) ? Xk : Xv;
    const float* bias = (z == 0) ? bq : (z == 1) ? bk : bv;
    const _Float16* Wz = Wf + (size_t)z * (HDIM * HDIM);
    _Float16* Y       = (z == 0) ? Qb : (z == 1) ? Kb : Vtb;

    const int n0 = blockIdx.x * 128;
    const int m0 = blockIdx.y * 128;

    __shared__ __align__(16) _Float16 As[128][40];  // [m][k], pad 40
    __shared__ __align__(16) _Float16 Bs[128][40];  // [n][k]

    const int t    = threadIdx.x;
    const int w    = t >> 6;
    const int lane = t & 63;
    const int quad = lane >> 4;
    const int lc   = lane & 15;
    const int wm   = (w >> 1) * 64;
    const int wn   = (w & 1) * 64;

    const f32x4 fzero = {0.f, 0.f, 0.f, 0.f};
    f32x4 acc[4][4];
#pragma unroll
    for (int i = 0; i < 4; i++)
#pragma unroll
        for (int j = 0; j < 4; j++) acc[i][j] = fzero;

    const int srow = t >> 2;   // 0..63 (two halves: srow, srow+64)
    const int sc   = t & 3;    // 8-elem chunk within the 32-elem k slice

    for (int k0 = 0; k0 < HDIM; k0 += 32) {
#pragma unroll
        for (int half = 0; half < 2; half++) {
            int row = srow + half * 64;
            {   // X: fp32 -> f16 inline
                const float* g = X + (size_t)(m0 + row) * HDIM + k0 + sc * 8;
                float4 a0 = *(const float4*)g;
                float4 a1 = *(const float4*)(g + 4);
                half8 v;
                v[0] = (_Float16)a0.x; v[1] = (_Float16)a0.y;
                v[2] = (_Float16)a0.z; v[3] = (_Float16)a0.w;
                v[4] = (_Float16)a1.x; v[5] = (_Float16)a1.y;
                v[6] = (_Float16)a1.z; v[7] = (_Float16)a1.w;
                *(half8*)&As[row][sc * 8] = v;
            }
            // W: already f16, straight 16B copy
            *(half8*)&Bs[row][sc * 8] =
                *(const half8*)(Wz + (size_t)(n0 + row) * HDIM + k0 + sc * 8);
        }
        __syncthreads();

        half8 af[4], bf[4];
#pragma unroll
        for (int mt = 0; mt < 4; mt++)
            af[mt] = *(const half8*)&As[wm + mt * 16 + lc][quad * 8];
#pragma unroll
        for (int nt = 0; nt < 4; nt++)
            bf[nt] = *(const half8*)&Bs[wn + nt * 16 + lc][quad * 8];
#pragma unroll
        for (int mt = 0; mt < 4; mt++)
#pragma unroll
            for (int nt = 0; nt < 4; nt++)
                acc[mt][nt] = __builtin_amdgcn_mfma_f32_16x16x32_f16(
                    af[mt], bf[nt], acc[mt][nt], 0, 0, 0);
        __syncthreads();
    }

#pragma unroll
    for (int nt = 0; nt < 4; nt++) {
        const int n = n0 + wn + nt * 16 + lc;          // h*64 + d
        const float bv_ = bias[n];
        const int h = n >> 6, d = n & 63;
#pragma unroll
        for (int mt = 0; mt < 4; mt++) {
#pragma unroll
            for (int r = 0; r < 4; r++) {
                const int m = m0 + wm + mt * 16 + quad * 4 + r;   // b*S + s
                const int b = m >> 11, s = m & (S_LEN - 1);
                const int bh = b * NHEAD + h;
                _Float16 val = (_Float16)(acc[mt][nt][r] + bv_);
                if (z == 2)
                    Y[((size_t)bh * HD + d) * S_LEN + s] = val;          // V^T
                else
                    Y[((size_t)bh * S_LEN + s) * HD + d] = val;          // Q,K
            }
        }
    }
}

// ---------------------------------------------------------------------------
// Flash attention, transposed orientation (S^T = K.Q^T, O^T = V^T.P^T),
// 2x q-blocking: each wave owns 32 q-rows (two B-frag groups qg=0,1) so each
// K/V LDS fragment read feeds TWO MFMAs.  Block = 128 q-rows, 4 waves.
// Per-lane softmax (q = lc per qg): in-register reduce + shfl_xor 16/32.
// ---------------------------------------------------------------------------
__global__ __launch_bounds__(256) void flash_attn_mfma(
    const _Float16* __restrict__ Qb, const _Float16* __restrict__ Kb,
    const _Float16* __restrict__ Vtb, const int* __restrict__ mask,
    float* __restrict__ out)
{
    const int qt = blockIdx.x & 15;      // 16 q-tiles of 128
    const int bh = blockIdx.x >> 4;      // 0..31
    const int b  = bh >> 4;
    const int h  = bh & (NHEAD - 1);

    __shared__ __align__(16) _Float16 Ks [64][72];      // [key][d]
    __shared__ __align__(16) _Float16 Vts[64][72];      // [d][key]
    __shared__ __align__(16) _Float16 Ps [4][32][72];   // per-wave P, [q][key]
    __shared__ float biasS[64];                         // mask bias per key

    const int t    = threadIdx.x;
    const int w    = t >> 6;
    const int lane = t & 63;
    const int quad = lane >> 4;
    const int lc   = lane & 15;

    const _Float16* Kbase = Kb  + (size_t)bh * S_LEN * HD;
    const _Float16* Vbase = Vtb + (size_t)bh * HD * S_LEN;

    // Q B-frags: qg in {0,1}, q-row = qt*128 + w*32 + qg*16 + lc
    half8 qf[2][2];
#pragma unroll
    for (int qg = 0; qg < 2; qg++) {
        const int qrow = qt * 128 + w * 32 + qg * 16 + lc;
#pragma unroll
        for (int s = 0; s < 2; s++)
            qf[qg][s] = *(const half8*)(Qb + ((size_t)bh * S_LEN + qrow) * HD
                                        + s * 32 + quad * 8);
    }

    const f32x4 fzero = {0.f, 0.f, 0.f, 0.f};
    f32x4 o[2][4];                      // O^T per qg: d = nt*16+quad*4+r, q = lc
#pragma unroll
    for (int qg = 0; qg < 2; qg++)
#pragma unroll
        for (int nt = 0; nt < 4; nt++) o[qg][nt] = fzero;
    float mrun[2] = {-3.0e38f, -3.0e38f};
    float lrun[2] = {0.f, 0.f};

    for (int kt = 0; kt < S_LEN; kt += 64) {
        // stage 64x64 K and Vt tiles (512 chunks of 16B each, 2 per thread)
#pragma unroll
        for (int i = 0; i < 2; i++) {
            int c  = t + 256 * i;        // 0..511
            int rr = c >> 3;             // 0..63
            int cc = (c & 7) * 8;        // 0..56
            *(half8*)&Ks[rr][cc] =
                *(const half8*)(Kbase + (size_t)(kt + rr) * HD + cc);
            *(half8*)&Vts[rr][cc] =
                *(const half8*)(Vbase + (size_t)rr * S_LEN + kt + cc);
        }
        if (t < 64) biasS[t] = mask[b * S_LEN + kt + t] ? 0.f : NEGBIAS;
        __syncthreads();

        // S^T = K.Q^T : each kf read feeds both qg MFMAs
        f32x4 scf[2][4];
#pragma unroll
        for (int qg = 0; qg < 2; qg++)
#pragma unroll
            for (int tt = 0; tt < 4; tt++) scf[qg][tt] = fzero;
#pragma unroll
        for (int s = 0; s < 2; s++) {
#pragma unroll
            for (int tt = 0; tt < 4; tt++) {
                half8 kf = *(const half8*)&Ks[tt * 16 + lc][s * 32 + quad * 8];
                scf[0][tt] = __builtin_amdgcn_mfma_f32_16x16x32_f16(kf, qf[0][s], scf[0][tt], 0, 0, 0);
                scf[1][tt] = __builtin_amdgcn_mfma_f32_16x16x32_f16(kf, qf[1][s], scf[1][tt], 0, 0, 0);
            }
        }

        // mask bias: score (tt,r) is key tt*16+quad*4+r (same addr per quad -> broadcast)
#pragma unroll
        for (int tt = 0; tt < 4; tt++) {
            float4 b4 = *(const float4*)&biasS[tt * 16 + quad * 4];
#pragma unroll
            for (int qg = 0; qg < 2; qg++) {
                scf[qg][tt][0] += b4.x; scf[qg][tt][1] += b4.y;
                scf[qg][tt][2] += b4.z; scf[qg][tt][3] += b4.w;
            }
        }

        // per-lane online softmax, one q-row per (qg, lc)
#pragma unroll
        for (int qg = 0; qg < 2; qg++) {
            float mx = scf[qg][0][0];
#pragma unroll
            for (int tt = 0; tt < 4; tt++)
#pragma unroll
                for (int r = 0; r < 4; r++) mx = fmaxf(mx, scf[qg][tt][r]);
            mx = fmaxf(mx, __shfl_xor(mx, 16));
            mx = fmaxf(mx, __shfl_xor(mx, 32));

            float mn = fmaxf(mrun[qg], mx);
            float al = __expf(mrun[qg] - mn);
            float ls = 0.f;
#pragma unroll
            for (int tt = 0; tt < 4; tt++)
#pragma unroll
                for (int r = 0; r < 4; r++) {
                    float p = __expf(scf[qg][tt][r] - mn);
                    scf[qg][tt][r] = p;
                    ls += p;
                }
            ls += __shfl_xor(ls, 16);
            ls += __shfl_xor(ls, 32);
            lrun[qg] = lrun[qg] * al + ls;
            mrun[qg] = mn;
#pragma unroll
            for (int nt = 0; nt < 4; nt++) {
                o[qg][nt][0] *= al; o[qg][nt][1] *= al;
                o[qg][nt][2] *= al; o[qg][nt][3] *= al;
            }

            // P rows (q-major): Ps[w][qg*16+lc][key], 8B packed writes
#pragma unroll
            for (int tt = 0; tt < 4; tt++) {
                half4 pk;
                pk[0] = (_Float16)scf[qg][tt][0]; pk[1] = (_Float16)scf[qg][tt][1];
                pk[2] = (_Float16)scf[qg][tt][2]; pk[3] = (_Float16)scf[qg][tt][3];
                *(half4*)&Ps[w][qg * 16 + lc][tt * 16 + quad * 4] = pk;
            }
        }

        // O^T += V^T.P^T : each vf read feeds both qg MFMAs
#pragma unroll
        for (int s = 0; s < 2; s++) {
            half8 pf0 = *(const half8*)&Ps[w][lc]     [s * 32 + quad * 8];
            half8 pf1 = *(const half8*)&Ps[w][16 + lc][s * 32 + quad * 8];
#pragma unroll
            for (int nt = 0; nt < 4; nt++) {
                half8 vf = *(const half8*)&Vts[nt * 16 + lc][s * 32 + quad * 8];
                o[0][nt] = __builtin_amdgcn_mfma_f32_16x16x32_f16(vf, pf0, o[0][nt], 0, 0, 0);
                o[1][nt] = __builtin_amdgcn_mfma_f32_16x16x32_f16(vf, pf1, o[1][nt], 0, 0, 0);
            }
        }
        __syncthreads();
    }

    // epilogue: lane owns q-row per qg; contiguous float4 stores
#pragma unroll
    for (int qg = 0; qg < 2; qg++) {
        const int qrow = qt * 128 + w * 32 + qg * 16 + lc;
        const float inv = 1.f / lrun[qg];
        const size_t rowb = ((size_t)b * S_LEN + qrow) * HDIM + h * HD;
#pragma unroll
        for (int nt = 0; nt < 4; nt++) {
            float4 v;
            v.x = o[qg][nt][0] * inv; v.y = o[qg][nt][1] * inv;
            v.z = o[qg][nt][2] * inv; v.w = o[qg][nt][3] * inv;
            *(float4*)&out[rowb + nt * 16 + quad * 4] = v;
        }
    }
}

// ---------------------------------------------------------------------------
extern "C" void kernel_launch(void* const* d_in, const int* in_sizes, int n_in,
                              void* d_out, int out_size, void* d_ws, size_t ws_size,
                              hipStream_t stream) {
    const float* query = (const float*)d_in[0];
    const float* key   = (const float*)d_in[1];
    const float* value = (const float*)d_in[2];
    const int*   mask  = (const int*)  d_in[3];
    const float* Wq    = (const float*)d_in[4];
    const float* bq    = (const float*)d_in[5];
    const float* Wk    = (const float*)d_in[6];
    const float* bk    = (const float*)d_in[7];
    const float* Wv    = (const float*)d_in[8];
    const float* bv    = (const float*)d_in[9];
    float* out = (float*)d_out;

    const size_t nElem = (size_t)BATCH * S_LEN * HDIM;          // 4M
    const size_t wElem = (size_t)HDIM * HDIM;                   // 1M
    if (ws_size < (3 * nElem + 3 * wElem) * sizeof(_Float16)) return;  // 30 MB
    _Float16* Qb  = (_Float16*)d_ws;
    _Float16* Kb  = Qb + nElem;
    _Float16* Vtb = Kb + nElem;
    _Float16* Wf  = Vtb + nElem;

    dim3 gcvt(wElem / (256 * 8), 3);                            // (512, 3)
    cvt_w<<<gcvt, 256, 0, stream>>>(Wq, Wk, Wv, Wf);

    dim3 gproj(HDIM / 128, (BATCH * S_LEN) / 128, 3);           // (8, 32, 3)
    proj_gemm_f16<<<gproj, 256, 0, stream>>>(query, key, value, Wf,
                                             bq, bk, bv, Qb, Kb, Vtb);

    flash_attn_mfma<<<BATCH * NHEAD * (S_LEN / 128), 256, 0, stream>>>(
        Qb, Kb, Vtb, mask, out);
}